// Round 11
// baseline (112.909 us; speedup 1.0000x reference)
//
#include <hip/hip_runtime.h>
#include <hip/hip_cooperative_groups.h>
#include <math.h>

namespace cg = cooperative_groups;

// Problem constants (from reference setup_inputs)
#define BS 32
#define CH 3
#define HH 512
#define WW 512
#define HWSZ (HH * WW)          // 262144
#define MOMENTUM 0.8
#define EPSILON 1e-5

// ================= fused cooperative kernel =================
// Index math (verified r8/r9/r10): for aligned f4 at in-plane element o,
// partners of o+1..o+3 are .w,.z,.y of aligned f4 at q1=(262144+508-o)&mask;
// partner of o is .x of aligned f4 at q2=(262144+(w0?0:512)-o)&mask.
// A-range = rows 0..255 (f4 mf=0..32767) with factor 2 (factor 1 for row 0,
// where both orderings appear); partner-row s2 via p1^2 (skip for row 0);
// row 256 handled by first 12288 threads (factor 1, a^2 only).
// Each thread RETAINS its 24 A-f4s + 24 partner-f4s in VGPRs across a grid
// sync, then normalizes and writes them -> x is read exactly once.
// Write coverage: a-writes = rows 0..255; p1-writes (skip h==0) = rows
// 257..511 (bijection mf <-> 65663-mf); row-256 extras write row 256.

constexpr int TPB   = 512;
constexpr int NBLK  = 256;
constexpr int NTHR  = NBLK * TPB;      // 131072
constexpr int JN    = 24;              // A-f4s per thread: 96*32768/131072
constexpr int R256  = BS * CH * (WW / 4);  // 12288

__global__ __launch_bounds__(TPB, 2) void fused_kernel(
    const float* __restrict__ x, const float* __restrict__ gamma,
    const float* __restrict__ beta, const float* __restrict__ rmean,
    const float* __restrict__ rvar, float* __restrict__ out,
    float* __restrict__ ws) {
    const int tid = threadIdx.x;
    const int g   = blockIdx.x * TPB + tid;
    const int p0  = g >> 15;           // starting plane 0..3 (block-uniform)
    const int mf  = g & 32767;         // in-plane A f4 index (rows 0..255)
    const int h   = mf >> 7;
    const bool w0 = (mf & 127) == 0;
    const int o   = mf * 4;
    const int q1  = (HWSZ + 508 - o) & (HWSZ - 1);
    const int q2  = (HWSZ + (w0 ? 0 : 512) - o) & (HWSZ - 1);
    const float f3 = (h == 0) ? 1.f : 2.f;
    const float fpp = (h == 0) ? 0.f : 1.f;

    float4 a[JN], p[JN];
    float sb1[3] = {0.f, 0.f, 0.f};
    float sb2[3] = {0.f, 0.f, 0.f};
    float sb3[3] = {0.f, 0.f, 0.f};

    // ---- phase A: load + stats; retain a[], p[] (plane = p0 + 4j) ----
#pragma unroll
    for (int j = 0; j < JN; ++j) {
        const float* bp = x + (size_t)(p0 + 4 * j) * HWSZ;
        a[j] = *reinterpret_cast<const float4*>(bp + o);
        p[j] = *reinterpret_cast<const float4*>(bp + q1);
        const float4 c = *reinterpret_cast<const float4*>(bp + q2);
        const float4 A = a[j], P = p[j];
        const float asq = A.x * A.x + A.y * A.y + A.z * A.z + A.w * A.w;
        const float psq = P.x * P.x + P.y * P.y + P.z * P.z + P.w * P.w;
        const float prd = A.x * c.x + A.y * P.w + A.z * P.z + A.w * P.y;
        sb2[j % 3] += asq + fpp * psq;
        sb3[j % 3] += f3 * prd;
        if (mf == 0) sb1[j % 3] += A.x;   // x[plane,0,0]
    }

    // ---- row-256 extra f4 (first 12288 threads), r10 tail verbatim ----
    const bool ex = (g < R256);
    float4 a6 = make_float4(0.f, 0.f, 0.f, 0.f);
    int ch6 = 0;
    size_t o6g = 0;
    if (ex) {
        const int pl = g >> 7;         // plane 0..95
        const int cf = g & 127;
        const int oo = 131072 + 4 * cf;
        const bool w06 = (cf == 0);
        const int qq1 = (HWSZ + 508 - oo) & (HWSZ - 1);
        const int qq2 = (HWSZ + (w06 ? 0 : 512) - oo) & (HWSZ - 1);
        const float* bp = x + (size_t)pl * HWSZ;
        a6 = *reinterpret_cast<const float4*>(bp + oo);
        const float4 P = *reinterpret_cast<const float4*>(bp + qq1);
        const float4 c = *reinterpret_cast<const float4*>(bp + qq2);
        const float asq = a6.x * a6.x + a6.y * a6.y + a6.z * a6.z + a6.w * a6.w;
        const float prd = a6.x * c.x + a6.y * P.w + a6.z * P.z + a6.w * P.y;
        ch6 = pl % 3;
        const int b6 = (ch6 - (p0 % 3) + 3) % 3;   // bucket with channel ch6
        if (b6 == 0)      { sb2[0] += asq; sb3[0] += prd; }
        else if (b6 == 1) { sb2[1] += asq; sb3[1] += prd; }
        else              { sb2[2] += asq; sb3[2] += prd; }
        o6g = (size_t)pl * HWSZ + oo;
    }

    // ---- map buckets -> channels: channel(b) = (p0 + b) % 3 ----
    float v[9];
    {
        const int r = p0 % 3;
        if (r == 0) {
            v[0]=sb1[0]; v[1]=sb2[0]; v[2]=sb3[0];
            v[3]=sb1[1]; v[4]=sb2[1]; v[5]=sb3[1];
            v[6]=sb1[2]; v[7]=sb2[2]; v[8]=sb3[2];
        } else if (r == 1) {
            v[0]=sb1[2]; v[1]=sb2[2]; v[2]=sb3[2];
            v[3]=sb1[0]; v[4]=sb2[0]; v[5]=sb3[0];
            v[6]=sb1[1]; v[7]=sb2[1]; v[8]=sb3[1];
        } else {
            v[0]=sb1[1]; v[1]=sb2[1]; v[2]=sb3[1];
            v[3]=sb1[2]; v[4]=sb2[2]; v[5]=sb3[2];
            v[6]=sb1[0]; v[7]=sb2[0]; v[8]=sb3[0];
        }
    }

    // ---- block reduce 9 channel-major sums -> per-block partial ----
    __shared__ float red[8][9];
    __shared__ float ssh[6];
#pragma unroll
    for (int off = 32; off > 0; off >>= 1)
#pragma unroll
        for (int i = 0; i < 9; ++i) v[i] += __shfl_down(v[i], off);
    const int wv = tid >> 6, ln = tid & 63;
    if (ln == 0)
#pragma unroll
        for (int i = 0; i < 9; ++i) red[wv][i] = v[i];
    __syncthreads();
    if (tid == 0) {
        float t[9];
#pragma unroll
        for (int i = 0; i < 9; ++i)
            t[i] = red[0][i] + red[1][i] + red[2][i] + red[3][i]
                 + red[4][i] + red[5][i] + red[6][i] + red[7][i];
        float* bws = ws + (size_t)blockIdx.x * 12;
        *reinterpret_cast<float4*>(bws)     = make_float4(t[0], t[1], t[2], t[3]);
        *reinterpret_cast<float4*>(bws + 4) = make_float4(t[4], t[5], t[6], t[7]);
        *reinterpret_cast<float4*>(bws + 8) = make_float4(t[8], 0.f, 0.f, 0.f);
    }
    __threadfence();
    cg::this_grid().sync();

    // ---- global reduce of 256 partials + scale/shift (inline finalize) ----
    float u[9] = {0.f,0.f,0.f,0.f,0.f,0.f,0.f,0.f,0.f};
    if (tid < NBLK) {
        const float* bws = ws + (size_t)tid * 12;
        const float4 A = *reinterpret_cast<const float4*>(bws);
        const float4 B = *reinterpret_cast<const float4*>(bws + 4);
        const float4 C = *reinterpret_cast<const float4*>(bws + 8);
        u[0]=A.x; u[1]=A.y; u[2]=A.z; u[3]=A.w;
        u[4]=B.x; u[5]=B.y; u[6]=B.z; u[7]=B.w; u[8]=C.x;
    }
#pragma unroll
    for (int off = 32; off > 0; off >>= 1)
#pragma unroll
        for (int i = 0; i < 9; ++i) u[i] += __shfl_down(u[i], off);
    if (ln == 0)
#pragma unroll
        for (int i = 0; i < 9; ++i) red[wv][i] = u[i];
    __syncthreads();
    if (tid == 0) {
#pragma unroll
        for (int c = 0; c < CH; ++c) {
            const double S1 = (double)(red[0][3*c+0] + red[1][3*c+0] + red[2][3*c+0] + red[3][3*c+0]);
            const double S2 = (double)(red[0][3*c+1] + red[1][3*c+1] + red[2][3*c+1] + red[3][3*c+1]);
            const double S3 = (double)(red[0][3*c+2] + red[1][3*c+2] + red[2][3*c+2] + red[3][3*c+2]);
            const double N = (double)BS * (double)HWSZ;
            const double mean = S1 / N;
            const double ex2  = (S2 + S3) / (2.0 * N * (double)HWSZ);
            const double var  = ex2 - mean * mean;
            const double rm = (double)rmean[c] * MOMENTUM + (1.0 - MOMENTUM) * mean;
            const double rv = (double)rvar[c]  * MOMENTUM + (1.0 - MOMENTUM) * var;
            const double inv_std = 1.0 / sqrt(rv + EPSILON);
            const float scale = (float)((double)gamma[c] * inv_std);
            const float shift = (float)((double)beta[c] - (double)scale * rm);
            ssh[2*c]   = scale;
            ssh[2*c+1] = shift;
        }
    }
    __syncthreads();

    // ---- phase B: normalize retained registers, write out ----
    float sc[3], sh[3];
#pragma unroll
    for (int b = 0; b < 3; ++b) {
        const int ch = (p0 + b) % 3;
        sc[b] = ssh[2*ch]; sh[b] = ssh[2*ch+1];
    }
#pragma unroll
    for (int j = 0; j < JN; ++j) {
        float* bo = out + (size_t)(p0 + 4 * j) * HWSZ;
        const float s = sc[j % 3], t = sh[j % 3];
        const float4 A = a[j];
        float4 oa;
        oa.x = fmaf(A.x, s, t); oa.y = fmaf(A.y, s, t);
        oa.z = fmaf(A.z, s, t); oa.w = fmaf(A.w, s, t);
        *reinterpret_cast<float4*>(bo + o) = oa;
        if (h != 0) {
            const float4 P = p[j];
            float4 op;
            op.x = fmaf(P.x, s, t); op.y = fmaf(P.y, s, t);
            op.z = fmaf(P.z, s, t); op.w = fmaf(P.w, s, t);
            *reinterpret_cast<float4*>(bo + q1) = op;
        }
    }
    if (ex) {
        const float s = ssh[2*ch6], t = ssh[2*ch6+1];
        float4 oa;
        oa.x = fmaf(a6.x, s, t); oa.y = fmaf(a6.y, s, t);
        oa.z = fmaf(a6.z, s, t); oa.w = fmaf(a6.w, s, t);
        *reinterpret_cast<float4*>(out + o6g) = oa;
    }
}

// ================= fallback: r10-verified 3-kernel path =================
constexpr int BPP = 16;
constexpr int ROWS_PER_BLK = 16;
constexpr int STAT_THREADS = 256;
constexpr int F4_PER_THREAD = ROWS_PER_BLK * (WW / 4) / STAT_THREADS;  // 8
constexpr int BATCH = 4;
constexpr int NBATCH = F4_PER_THREAD / BATCH;
constexpr int NBLOCKS = BS * CH * BPP;         // 1536

__global__ __launch_bounds__(STAT_THREADS) void stats_kernel(
    const float* __restrict__ x, float4* __restrict__ partials) {
    const int plane = blockIdx.x / BPP;
    const int blk   = blockIdx.x % BPP;
    const float* __restrict__ base = x + (size_t)plane * HWSZ;
    const int tid = threadIdx.x;
    const int h0  = blk * ROWS_PER_BLK;
    float s1 = 0.f, s2 = 0.f, s3 = 0.f;
    for (int nb = 0; nb < NBATCH; ++nb) {
        float4 a[BATCH], p1[BATCH], p2[BATCH];
#pragma unroll
        for (int j = 0; j < BATCH; ++j) {
            const int idx  = tid + (nb * BATCH + j) * STAT_THREADS;
            const int r    = idx >> 7;
            const int col4 = idx & 127;
            const int o    = ((h0 + r) << 9) + (col4 << 2);
            const bool w0  = (col4 == 0);
            const int q1 = (HWSZ + 508 - o) & (HWSZ - 1);
            const int q2 = (HWSZ + (w0 ? 0 : 512) - o) & (HWSZ - 1);
            a[j]  = *reinterpret_cast<const float4*>(base + o);
            p1[j] = *reinterpret_cast<const float4*>(base + q1);
            p2[j] = *reinterpret_cast<const float4*>(base + q2);
        }
#pragma unroll
        for (int j = 0; j < BATCH; ++j) {
            const int idx = tid + (nb * BATCH + j) * STAT_THREADS;
            const int h   = h0 + (idx >> 7);
            const float4 a_ = a[j], p1_ = p1[j], p2_ = p2[j];
            const float asq = a_.x*a_.x + a_.y*a_.y + a_.z*a_.z + a_.w*a_.w;
            const float qsq = p1_.x*p1_.x + p1_.y*p1_.y + p1_.z*p1_.z + p1_.w*p1_.w;
            const float prd = a_.x*p2_.x + a_.y*p1_.w + a_.z*p1_.z + a_.w*p1_.y;
            const float two = (h == 0) ? 0.f : 1.f;
            s2 += asq + two * qsq;
            s3 += (h == 0 ? 1.f : 2.f) * prd;
            if (h == 0 && idx == 0) s1 += a_.x;
        }
    }
    if (blk == 0 && tid < 128) {
        const int o  = 256 * WW + tid * 4;
        const bool w0 = (tid == 0);
        const int q1 = (HWSZ + 508 - o) & (HWSZ - 1);
        const int q2 = (HWSZ + (w0 ? 0 : 512) - o) & (HWSZ - 1);
        const float4 a_  = *reinterpret_cast<const float4*>(base + o);
        const float4 p1_ = *reinterpret_cast<const float4*>(base + q1);
        const float4 p2_ = *reinterpret_cast<const float4*>(base + q2);
        s2 += a_.x*a_.x + a_.y*a_.y + a_.z*a_.z + a_.w*a_.w;
        s3 += a_.x*p2_.x + a_.y*p1_.w + a_.z*p1_.z + a_.w*p1_.y;
    }
#pragma unroll
    for (int off = 32; off > 0; off >>= 1) {
        s1 += __shfl_down(s1, off);
        s2 += __shfl_down(s2, off);
        s3 += __shfl_down(s3, off);
    }
    __shared__ float red[3][4];
    const int lane = tid & 63, wv = tid >> 6;
    if (lane == 0) { red[0][wv] = s1; red[1][wv] = s2; red[2][wv] = s3; }
    __syncthreads();
    if (tid == 0) {
        float4 p;
        p.x = red[0][0] + red[0][1] + red[0][2] + red[0][3];
        p.y = red[1][0] + red[1][1] + red[1][2] + red[1][3];
        p.z = red[2][0] + red[2][1] + red[2][2] + red[2][3];
        p.w = 0.f;
        partials[blockIdx.x] = p;
    }
}

__global__ __launch_bounds__(256) void finalize_kernel(
    const float4* __restrict__ partials,
    const float* __restrict__ gamma, const float* __restrict__ beta,
    const float* __restrict__ rmean, const float* __restrict__ rvar,
    float* __restrict__ ss) {
    const int c = blockIdx.x;
    const int tid = threadIdx.x;
    const int per_c = BS * BPP;
    double t1 = 0.0, t2 = 0.0, t3 = 0.0;
    for (int k = tid; k < per_c; k += 256) {
        const int b = k / BPP, blk = k % BPP;
        const float4 p = partials[(b * CH + c) * BPP + blk];
        t1 += (double)p.x; t2 += (double)p.y; t3 += (double)p.z;
    }
#pragma unroll
    for (int off = 32; off > 0; off >>= 1) {
        t1 += __shfl_down(t1, off);
        t2 += __shfl_down(t2, off);
        t3 += __shfl_down(t3, off);
    }
    __shared__ double red[3][4];
    const int lane = tid & 63, wv = tid >> 6;
    if (lane == 0) { red[0][wv] = t1; red[1][wv] = t2; red[2][wv] = t3; }
    __syncthreads();
    if (tid == 0) {
        const double S1 = red[0][0] + red[0][1] + red[0][2] + red[0][3];
        const double S2 = red[1][0] + red[1][1] + red[1][2] + red[1][3];
        const double S3 = red[2][0] + red[2][1] + red[2][2] + red[2][3];
        const double N = (double)BS * (double)HWSZ;
        const double mean = S1 / N;
        const double ex2  = (S2 + S3) / (2.0 * N * (double)HWSZ);
        const double var  = ex2 - mean * mean;
        const double rm = (double)rmean[c] * MOMENTUM + (1.0 - MOMENTUM) * mean;
        const double rv = (double)rvar[c]  * MOMENTUM + (1.0 - MOMENTUM) * var;
        const double inv_std = 1.0 / sqrt(rv + EPSILON);
        const float scale = (float)((double)gamma[c] * inv_std);
        const float shift = (float)((double)beta[c] - (double)scale * rm);
        ss[c * 2 + 0] = scale;
        ss[c * 2 + 1] = shift;
    }
}

__global__ __launch_bounds__(256) void norm_kernel(
    const float* __restrict__ x, const float* __restrict__ ss,
    float* __restrict__ out) {
    float sc[CH], sh[CH];
#pragma unroll
    for (int c = 0; c < CH; ++c) { sc[c] = ss[c * 2]; sh[c] = ss[c * 2 + 1]; }
    const int n4 = BS * CH * HWSZ / 4;
    const int stride = gridDim.x * blockDim.x;
    for (int i4 = blockIdx.x * blockDim.x + threadIdx.x; i4 < n4; i4 += stride) {
        const int c = (i4 >> 16) % CH;
        const float4 v = reinterpret_cast<const float4*>(x)[i4];
        const float s = sc[c], t = sh[c];
        float4 o;
        o.x = fmaf(v.x, s, t); o.y = fmaf(v.y, s, t);
        o.z = fmaf(v.z, s, t); o.w = fmaf(v.w, s, t);
        reinterpret_cast<float4*>(out)[i4] = o;
    }
}

extern "C" void kernel_launch(void* const* d_in, const int* in_sizes, int n_in,
                              void* d_out, int out_size, void* d_ws, size_t ws_size,
                              hipStream_t stream) {
    const float* x     = (const float*)d_in[0];
    const float* gamma = (const float*)d_in[1];
    const float* beta  = (const float*)d_in[2];
    const float* rmean = (const float*)d_in[3];
    const float* rvar  = (const float*)d_in[4];
    float* out = (float*)d_out;
    float* ws  = (float*)d_ws;     // 256 blocks * 12 floats = 12 KiB

    void* args[] = {(void*)&x, (void*)&gamma, (void*)&beta, (void*)&rmean,
                    (void*)&rvar, (void*)&out, (void*)&ws};
    const hipError_t e = hipLaunchCooperativeKernel(
        (const void*)fused_kernel, dim3(NBLK), dim3(TPB), args, 0, stream);
    if (e == hipSuccess) return;

    // fallback: proven r10 path
    float4* partials = (float4*)d_ws;
    float*  ss = (float*)((char*)d_ws + NBLOCKS * 16);
    stats_kernel<<<NBLOCKS, STAT_THREADS, 0, stream>>>(x, partials);
    finalize_kernel<<<CH, 256, 0, stream>>>(partials, gamma, beta, rmean, rvar, ss);
    norm_kernel<<<2048, 256, 0, stream>>>(x, ss, out);
}

// Round 12
// 59.819 us; speedup vs baseline: 1.8875x; 1.8875x over previous
//
#include <hip/hip_runtime.h>
#include <math.h>

// Problem constants (from reference setup_inputs)
#define BS 32
#define CH 3
#define HH 512
#define WW 512
#define HWSZ (HH * WW)          // 262144
#define MOMENTUM 0.8
#define EPSILON 1e-5

// ================= fused persistent kernel =================
// Index math (verified r8..r11): for aligned f4 at in-plane element o,
// partners of o+1..o+3 are .w,.z,.y of aligned f4 at q1=(262144+508-o)&mask;
// partner of o is .x of aligned f4 at q2=(262144+(w0?0:512)-o)&mask.
// A-range = rows 0..255 (factor 2; row 0 factor 1), partner-row s2 via p1^2
// (skip h==0), row 256 by first 12288 threads (factor 1, a^2 only).
// Each thread retains its 24 A-f4s + 24 partner-f4s in VGPRs across a
// hand-rolled grid barrier, then normalizes and writes from registers:
// x read exactly once, out written exactly once (bijective coverage,
// verified r11 — r11 failed on SPILL, not correctness).
// Spill fixes vs r11: no cooperative-groups call (hand-rolled barrier),
// TPB=256 with launch_bounds(256,2) -> 256-VGPR budget.
// Host guards: localSizeBytes>0 or occupancy<2/CU  => r10 fallback path.

constexpr int TPB   = 256;
constexpr int NBLK  = 512;
constexpr int NTHR  = NBLK * TPB;          // 131072
constexpr int JN    = 24;                  // 96 planes * 32768 f4 / 131072
constexpr int R256  = BS * CH * (WW / 4);  // 12288
constexpr int CUS   = 256;
constexpr int CNT_OFF_BYTES = NBLK * 12 * 4;   // counter after partials (24576)

__global__ __launch_bounds__(TPB, 2) void fused_kernel(
    const float* __restrict__ x, const float* __restrict__ gamma,
    const float* __restrict__ beta, const float* __restrict__ rmean,
    const float* __restrict__ rvar, float* __restrict__ out,
    float* __restrict__ ws) {
    const int tid = threadIdx.x;
    const int g   = blockIdx.x * TPB + tid;
    const int p0  = g >> 15;           // starting plane 0..3
    const int mf  = g & 32767;         // in-plane A f4 index (rows 0..255)
    const int h   = mf >> 7;
    const bool w0 = (mf & 127) == 0;
    const int o   = mf * 4;
    const int q1  = (HWSZ + 508 - o) & (HWSZ - 1);
    const int q2  = (HWSZ + (w0 ? 0 : 512) - o) & (HWSZ - 1);
    const float f3  = (h == 0) ? 1.f : 2.f;
    const float fpp = (h == 0) ? 0.f : 1.f;

    float4 a[JN], p[JN];
    float sb1[3] = {0.f, 0.f, 0.f};
    float sb2[3] = {0.f, 0.f, 0.f};
    float sb3[3] = {0.f, 0.f, 0.f};

    // ---- phase A: load + stats; retain a[], p[] (plane = p0 + 4j) ----
#pragma unroll
    for (int j = 0; j < JN; ++j) {
        const float* bp = x + (size_t)(p0 + 4 * j) * HWSZ;
        a[j] = *reinterpret_cast<const float4*>(bp + o);
        p[j] = *reinterpret_cast<const float4*>(bp + q1);
        const float4 c = *reinterpret_cast<const float4*>(bp + q2);
        const float4 A = a[j], P = p[j];
        const float asq = A.x * A.x + A.y * A.y + A.z * A.z + A.w * A.w;
        const float psq = P.x * P.x + P.y * P.y + P.z * P.z + P.w * P.w;
        const float prd = A.x * c.x + A.y * P.w + A.z * P.z + A.w * P.y;
        sb2[j % 3] += asq + fpp * psq;
        sb3[j % 3] += f3 * prd;
        if (mf == 0) sb1[j % 3] += A.x;   // x[plane,0,0]
    }

    // ---- row-256 extra f4 (first 12288 threads) ----
    const bool ex = (g < R256);
    float4 a6 = make_float4(0.f, 0.f, 0.f, 0.f);
    int ch6 = 0;
    size_t o6g = 0;
    if (ex) {
        const int pl = g >> 7;         // plane 0..95
        const int cf = g & 127;
        const int oo = 131072 + 4 * cf;
        const bool w06 = (cf == 0);
        const int qq1 = (HWSZ + 508 - oo) & (HWSZ - 1);
        const int qq2 = (HWSZ + (w06 ? 0 : 512) - oo) & (HWSZ - 1);
        const float* bp = x + (size_t)pl * HWSZ;
        a6 = *reinterpret_cast<const float4*>(bp + oo);
        const float4 P = *reinterpret_cast<const float4*>(bp + qq1);
        const float4 c = *reinterpret_cast<const float4*>(bp + qq2);
        const float asq = a6.x * a6.x + a6.y * a6.y + a6.z * a6.z + a6.w * a6.w;
        const float prd = a6.x * c.x + a6.y * P.w + a6.z * P.z + a6.w * P.y;
        ch6 = pl % 3;
        const int b6 = (ch6 - (p0 % 3) + 3) % 3;
        if (b6 == 0)      { sb2[0] += asq; sb3[0] += prd; }
        else if (b6 == 1) { sb2[1] += asq; sb3[1] += prd; }
        else              { sb2[2] += asq; sb3[2] += prd; }
        o6g = (size_t)pl * HWSZ + oo;
    }

    // ---- map buckets -> channels: channel(b) = (p0 + b) % 3 ----
    float v[9];
    {
        const int r = p0 % 3;
        if (r == 0) {
            v[0]=sb1[0]; v[1]=sb2[0]; v[2]=sb3[0];
            v[3]=sb1[1]; v[4]=sb2[1]; v[5]=sb3[1];
            v[6]=sb1[2]; v[7]=sb2[2]; v[8]=sb3[2];
        } else if (r == 1) {
            v[0]=sb1[2]; v[1]=sb2[2]; v[2]=sb3[2];
            v[3]=sb1[0]; v[4]=sb2[0]; v[5]=sb3[0];
            v[6]=sb1[1]; v[7]=sb2[1]; v[8]=sb3[1];
        } else {
            v[0]=sb1[1]; v[1]=sb2[1]; v[2]=sb3[1];
            v[3]=sb1[2]; v[4]=sb2[2]; v[5]=sb3[2];
            v[6]=sb1[0]; v[7]=sb2[0]; v[8]=sb3[0];
        }
    }

    // ---- block reduce (4 waves) -> per-block partial in ws ----
    __shared__ float red[4][9];
    __shared__ float ssh[6];
#pragma unroll
    for (int off = 32; off > 0; off >>= 1)
#pragma unroll
        for (int i = 0; i < 9; ++i) v[i] += __shfl_down(v[i], off);
    const int wv = tid >> 6, ln = tid & 63;
    if (ln == 0)
#pragma unroll
        for (int i = 0; i < 9; ++i) red[wv][i] = v[i];
    __syncthreads();

    int* cnt = (int*)((char*)ws + CNT_OFF_BYTES);
    if (tid == 0) {
        float* bws = ws + (size_t)blockIdx.x * 12;
#pragma unroll
        for (int i = 0; i < 9; ++i) {
            const float t = red[0][i] + red[1][i] + red[2][i] + red[3][i];
            __hip_atomic_store(bws + i, t, __ATOMIC_RELEASE,
                               __HIP_MEMORY_SCOPE_AGENT);
        }
        // ---- grid barrier (device-scope, cross-XCD safe) ----
        __hip_atomic_fetch_add(cnt, 1, __ATOMIC_ACQ_REL,
                               __HIP_MEMORY_SCOPE_AGENT);
        while (__hip_atomic_load(cnt, __ATOMIC_ACQUIRE,
                                 __HIP_MEMORY_SCOPE_AGENT) < NBLK)
            __builtin_amdgcn_s_sleep(8);
    }
    __syncthreads();

    // ---- global reduce of 512 partials + scale/shift (every block) ----
    float u[9] = {0.f,0.f,0.f,0.f,0.f,0.f,0.f,0.f,0.f};
    for (int s = tid; s < NBLK; s += TPB) {
        const float* bws = ws + (size_t)s * 12;
#pragma unroll
        for (int i = 0; i < 9; ++i)
            u[i] += __hip_atomic_load(bws + i, __ATOMIC_ACQUIRE,
                                      __HIP_MEMORY_SCOPE_AGENT);
    }
#pragma unroll
    for (int off = 32; off > 0; off >>= 1)
#pragma unroll
        for (int i = 0; i < 9; ++i) u[i] += __shfl_down(u[i], off);
    if (ln == 0)
#pragma unroll
        for (int i = 0; i < 9; ++i) red[wv][i] = u[i];
    __syncthreads();
    if (tid == 0) {
#pragma unroll
        for (int c = 0; c < CH; ++c) {
            const double S1 = (double)(red[0][3*c+0] + red[1][3*c+0] + red[2][3*c+0] + red[3][3*c+0]);
            const double S2 = (double)(red[0][3*c+1] + red[1][3*c+1] + red[2][3*c+1] + red[3][3*c+1]);
            const double S3 = (double)(red[0][3*c+2] + red[1][3*c+2] + red[2][3*c+2] + red[3][3*c+2]);
            const double N = (double)BS * (double)HWSZ;
            const double mean = S1 / N;
            const double ex2  = (S2 + S3) / (2.0 * N * (double)HWSZ);
            const double var  = ex2 - mean * mean;
            const double rm = (double)rmean[c] * MOMENTUM + (1.0 - MOMENTUM) * mean;
            const double rv = (double)rvar[c]  * MOMENTUM + (1.0 - MOMENTUM) * var;
            const double inv_std = 1.0 / sqrt(rv + EPSILON);
            const float scale = (float)((double)gamma[c] * inv_std);
            const float shift = (float)((double)beta[c] - (double)scale * rm);
            ssh[2*c]   = scale;
            ssh[2*c+1] = shift;
        }
    }
    __syncthreads();

    // ---- phase B: normalize retained registers, write out ----
    float sc[3], sh[3];
#pragma unroll
    for (int b = 0; b < 3; ++b) {
        const int ch = (p0 + b) % 3;
        sc[b] = ssh[2*ch]; sh[b] = ssh[2*ch+1];
    }
#pragma unroll
    for (int j = 0; j < JN; ++j) {
        float* bo = out + (size_t)(p0 + 4 * j) * HWSZ;
        const float s = sc[j % 3], t = sh[j % 3];
        const float4 A = a[j];
        float4 oa;
        oa.x = fmaf(A.x, s, t); oa.y = fmaf(A.y, s, t);
        oa.z = fmaf(A.z, s, t); oa.w = fmaf(A.w, s, t);
        *reinterpret_cast<float4*>(bo + o) = oa;
        if (h != 0) {
            const float4 P = p[j];
            float4 op;
            op.x = fmaf(P.x, s, t); op.y = fmaf(P.y, s, t);
            op.z = fmaf(P.z, s, t); op.w = fmaf(P.w, s, t);
            *reinterpret_cast<float4*>(bo + q1) = op;
        }
    }
    if (ex) {
        const float s = ssh[2*ch6], t = ssh[2*ch6+1];
        float4 oa;
        oa.x = fmaf(a6.x, s, t); oa.y = fmaf(a6.y, s, t);
        oa.z = fmaf(a6.z, s, t); oa.w = fmaf(a6.w, s, t);
        *reinterpret_cast<float4*>(out + o6g) = oa;
    }
}

// ================= fallback: r10-verified 3-kernel path =================
constexpr int BPP = 16;
constexpr int ROWS_PER_BLK = 16;
constexpr int STAT_THREADS = 256;
constexpr int F4_PER_THREAD = ROWS_PER_BLK * (WW / 4) / STAT_THREADS;  // 8
constexpr int BATCH = 4;
constexpr int NBATCH = F4_PER_THREAD / BATCH;
constexpr int NBLOCKS = BS * CH * BPP;         // 1536

__global__ __launch_bounds__(STAT_THREADS) void stats_kernel(
    const float* __restrict__ x, float4* __restrict__ partials) {
    const int plane = blockIdx.x / BPP;
    const int blk   = blockIdx.x % BPP;
    const float* __restrict__ base = x + (size_t)plane * HWSZ;
    const int tid = threadIdx.x;
    const int h0  = blk * ROWS_PER_BLK;
    float s1 = 0.f, s2 = 0.f, s3 = 0.f;
    for (int nb = 0; nb < NBATCH; ++nb) {
        float4 a[BATCH], p1[BATCH], p2[BATCH];
#pragma unroll
        for (int j = 0; j < BATCH; ++j) {
            const int idx  = tid + (nb * BATCH + j) * STAT_THREADS;
            const int r    = idx >> 7;
            const int col4 = idx & 127;
            const int o    = ((h0 + r) << 9) + (col4 << 2);
            const bool w0  = (col4 == 0);
            const int q1 = (HWSZ + 508 - o) & (HWSZ - 1);
            const int q2 = (HWSZ + (w0 ? 0 : 512) - o) & (HWSZ - 1);
            a[j]  = *reinterpret_cast<const float4*>(base + o);
            p1[j] = *reinterpret_cast<const float4*>(base + q1);
            p2[j] = *reinterpret_cast<const float4*>(base + q2);
        }
#pragma unroll
        for (int j = 0; j < BATCH; ++j) {
            const int idx = tid + (nb * BATCH + j) * STAT_THREADS;
            const int h   = h0 + (idx >> 7);
            const float4 a_ = a[j], p1_ = p1[j], p2_ = p2[j];
            const float asq = a_.x*a_.x + a_.y*a_.y + a_.z*a_.z + a_.w*a_.w;
            const float qsq = p1_.x*p1_.x + p1_.y*p1_.y + p1_.z*p1_.z + p1_.w*p1_.w;
            const float prd = a_.x*p2_.x + a_.y*p1_.w + a_.z*p1_.z + a_.w*p1_.y;
            const float two = (h == 0) ? 0.f : 1.f;
            s2 += asq + two * qsq;
            s3 += (h == 0 ? 1.f : 2.f) * prd;
            if (h == 0 && idx == 0) s1 += a_.x;
        }
    }
    if (blk == 0 && tid < 128) {
        const int o  = 256 * WW + tid * 4;
        const bool w0 = (tid == 0);
        const int q1 = (HWSZ + 508 - o) & (HWSZ - 1);
        const int q2 = (HWSZ + (w0 ? 0 : 512) - o) & (HWSZ - 1);
        const float4 a_  = *reinterpret_cast<const float4*>(base + o);
        const float4 p1_ = *reinterpret_cast<const float4*>(base + q1);
        const float4 p2_ = *reinterpret_cast<const float4*>(base + q2);
        s2 += a_.x*a_.x + a_.y*a_.y + a_.z*a_.z + a_.w*a_.w;
        s3 += a_.x*p2_.x + a_.y*p1_.w + a_.z*p1_.z + a_.w*p1_.y;
    }
#pragma unroll
    for (int off = 32; off > 0; off >>= 1) {
        s1 += __shfl_down(s1, off);
        s2 += __shfl_down(s2, off);
        s3 += __shfl_down(s3, off);
    }
    __shared__ float red[3][4];
    const int lane = tid & 63, wv = tid >> 6;
    if (lane == 0) { red[0][wv] = s1; red[1][wv] = s2; red[2][wv] = s3; }
    __syncthreads();
    if (tid == 0) {
        float4 p;
        p.x = red[0][0] + red[0][1] + red[0][2] + red[0][3];
        p.y = red[1][0] + red[1][1] + red[1][2] + red[1][3];
        p.z = red[2][0] + red[2][1] + red[2][2] + red[2][3];
        p.w = 0.f;
        partials[blockIdx.x] = p;
    }
}

__global__ __launch_bounds__(256) void finalize_kernel(
    const float4* __restrict__ partials,
    const float* __restrict__ gamma, const float* __restrict__ beta,
    const float* __restrict__ rmean, const float* __restrict__ rvar,
    float* __restrict__ ss) {
    const int c = blockIdx.x;
    const int tid = threadIdx.x;
    const int per_c = BS * BPP;
    double t1 = 0.0, t2 = 0.0, t3 = 0.0;
    for (int k = tid; k < per_c; k += 256) {
        const int b = k / BPP, blk = k % BPP;
        const float4 p = partials[(b * CH + c) * BPP + blk];
        t1 += (double)p.x; t2 += (double)p.y; t3 += (double)p.z;
    }
#pragma unroll
    for (int off = 32; off > 0; off >>= 1) {
        t1 += __shfl_down(t1, off);
        t2 += __shfl_down(t2, off);
        t3 += __shfl_down(t3, off);
    }
    __shared__ double red[3][4];
    const int lane = tid & 63, wv = tid >> 6;
    if (lane == 0) { red[0][wv] = t1; red[1][wv] = t2; red[2][wv] = t3; }
    __syncthreads();
    if (tid == 0) {
        const double S1 = red[0][0] + red[0][1] + red[0][2] + red[0][3];
        const double S2 = red[1][0] + red[1][1] + red[1][2] + red[1][3];
        const double S3 = red[2][0] + red[2][1] + red[2][2] + red[2][3];
        const double N = (double)BS * (double)HWSZ;
        const double mean = S1 / N;
        const double ex2  = (S2 + S3) / (2.0 * N * (double)HWSZ);
        const double var  = ex2 - mean * mean;
        const double rm = (double)rmean[c] * MOMENTUM + (1.0 - MOMENTUM) * mean;
        const double rv = (double)rvar[c]  * MOMENTUM + (1.0 - MOMENTUM) * var;
        const double inv_std = 1.0 / sqrt(rv + EPSILON);
        const float scale = (float)((double)gamma[c] * inv_std);
        const float shift = (float)((double)beta[c] - (double)scale * rm);
        ss[c * 2 + 0] = scale;
        ss[c * 2 + 1] = shift;
    }
}

__global__ __launch_bounds__(256) void norm_kernel(
    const float* __restrict__ x, const float* __restrict__ ss,
    float* __restrict__ out) {
    float sc[CH], sh[CH];
#pragma unroll
    for (int c = 0; c < CH; ++c) { sc[c] = ss[c * 2]; sh[c] = ss[c * 2 + 1]; }
    const int n4 = BS * CH * HWSZ / 4;
    const int stride = gridDim.x * blockDim.x;
    for (int i4 = blockIdx.x * blockDim.x + threadIdx.x; i4 < n4; i4 += stride) {
        const int c = (i4 >> 16) % CH;
        const float4 v = reinterpret_cast<const float4*>(x)[i4];
        const float s = sc[c], t = sh[c];
        float4 o;
        o.x = fmaf(v.x, s, t); o.y = fmaf(v.y, s, t);
        o.z = fmaf(v.z, s, t); o.w = fmaf(v.w, s, t);
        reinterpret_cast<float4*>(out)[i4] = o;
    }
}

extern "C" void kernel_launch(void* const* d_in, const int* in_sizes, int n_in,
                              void* d_out, int out_size, void* d_ws, size_t ws_size,
                              hipStream_t stream) {
    const float* x     = (const float*)d_in[0];
    const float* gamma = (const float*)d_in[1];
    const float* beta  = (const float*)d_in[2];
    const float* rmean = (const float*)d_in[3];
    const float* rvar  = (const float*)d_in[4];
    float* out = (float*)d_out;
    float* ws  = (float*)d_ws;

    // ---- guards: no spill, full co-residency, enough workspace ----
    bool use_fused = (ws_size >= CNT_OFF_BYTES + 64);
    if (use_fused) {
        hipFuncAttributes attr;
        if (hipFuncGetAttributes(&attr, (const void*)fused_kernel) != hipSuccess
            || attr.localSizeBytes > 0)
            use_fused = false;
    }
    if (use_fused) {
        int maxb = 0;
        if (hipOccupancyMaxActiveBlocksPerMultiprocessor(
                &maxb, (const void*)fused_kernel, TPB, 0) != hipSuccess
            || maxb * CUS < NBLK)
            use_fused = false;
    }

    if (use_fused) {
        hipMemsetAsync((char*)d_ws + CNT_OFF_BYTES, 0, 4, stream);
        fused_kernel<<<NBLK, TPB, 0, stream>>>(x, gamma, beta, rmean, rvar,
                                               out, ws);
        return;
    }

    // fallback: proven r10 path
    float4* partials = (float4*)d_ws;
    float*  ss = (float*)((char*)d_ws + NBLOCKS * 16);
    stats_kernel<<<NBLOCKS, STAT_THREADS, 0, stream>>>(x, partials);
    finalize_kernel<<<CH, 256, 0, stream>>>(partials, gamma, beta, rmean, rvar, ss);
    norm_kernel<<<2048, 256, 0, stream>>>(x, ss, out);
}